// Round 18
// baseline (336.783 us; speedup 1.0000x reference)
//
#include <hip/hip_runtime.h>

typedef __attribute__((ext_vector_type(8))) short bf16x8;
typedef __attribute__((ext_vector_type(4))) float f32x4;
typedef unsigned short u16;
typedef unsigned int u32;

#define NTOK 144
#define CDIM 192
#define NH 6
#define CH 32
#define C3 576
#define NWIN 64
#define WLON 15
#define SCALE 0.17677669529663687f
#define LOG2E 1.4426950408889634f

// w1t panels stored pre-padded to the LDS image: 9 panels x [64 rows][200 u16] (pad zeroed)
#define BPAD 200
#define PANEL_BYTES 25600u     // 64*200*2

// ws layout (bytes)
#define OFF_W1T  0u            // 9*25600 = 230400
#define OFF_W2T  230400u       // 192*192*2 = 73728
#define OFF_COMB 304128u       // bf16 frag layout: 384*5184*4*2 = 15925248
#define OFF_Q    16229376u     // 960*6*144*32*2 = 53084160
#define OFF_K    69313536u
#define OFF_V    122397696u    // stored transposed: [b][h][ch][144]

__device__ __forceinline__ u16 f2b(float f){
  u32 u = __float_as_uint(f);
  u32 r = u + 0x7FFFu + ((u >> 16) & 1u);   // RNE
  return (u16)(r >> 16);
}
__device__ __forceinline__ u32 pk2(float a, float b){
  return (u32)f2b(a) | ((u32)f2b(b) << 16);
}
__device__ __forceinline__ void gload_lds16(const void* g, void* l){
  __builtin_amdgcn_global_load_lds(
      (const __attribute__((address_space(1))) unsigned int*)g,
      (__attribute__((address_space(3))) unsigned int*)l, 16, 0, 0);
}

// ---------------- prep: w1 -> padded bf16 panels (LDS image); w2 -> plain transposed bf16
extern "C" __global__ __launch_bounds__(256) void prep_weights(
    const float* __restrict__ w1, const float* __restrict__ w2,
    u16* __restrict__ w1tp, u16* __restrict__ w2t){
  int idx = blockIdx.x * 256 + threadIdx.x;
  if (idx < CDIM * C3){
    int k = idx / C3;  int c = idx - k * C3;
    w1tp[(size_t)c * BPAD + k] = f2b(w1[idx]);       // panel nt = rows c in [nt*64,(nt+1)*64)
  }
  if (idx < C3 * 8){                                  // zero row pads (cols 192..199)
    int c = idx >> 3, p = idx & 7;
    w1tp[(size_t)c * BPAD + CDIM + p] = 0;
  }
  if (idx < CDIM * CDIM){ int k = idx / CDIM; int c = idx - k * CDIM; w2t[c * CDIM + k] = f2b(w2[idx]); }
}

// ---------------- prep: comb (bias+mask)*LOG2E as bf16 in MFMA C-fragment layout.
extern "C" __global__ __launch_bounds__(192) void prep_comb(
    const float* __restrict__ bt, const float* __restrict__ mask,
    const int* __restrict__ pidx, u16* __restrict__ comb){
  int nwh = blockIdx.x;                 // 0..383 = nw*6+h
  int nw = nwh / NH, h = nwh - nw * NH;
  int tl = blockIdx.y * 192 + threadIdx.x;   // 0..5183 = (ti*9+nt)*64+lane
  int ti = tl / 576;
  int rem = tl - ti * 576;
  int nt = rem >> 6, lane = rem & 63;
  int ib = ti * 16 + ((lane >> 4) << 2);
  int j  = nt * 16 + (lane & 15);
  const float* mrow = mask + (size_t)(nw * WLON) * (NTOK * NTOK);
  float v[4];
  #pragma unroll
  for (int r = 0; r < 4; ++r){
    int e = (ib + r) * NTOK + j;
    int pi = pidx[e];
    v[r] = (bt[((size_t)pi * NWIN + nw) * NH + h] + mrow[e]) * LOG2E;
  }
  uint2 out; out.x = pk2(v[0], v[1]); out.y = pk2(v[2], v[3]);
  *reinterpret_cast<uint2*>(comb + ((size_t)nwh * 5184 + tl) * 4) = out;
}

// ---------------- K1: qkv v5 — 2D grid (row-tile x panel). Block = 128 rows x 64 cols of
// one nt panel: single gll staging shot, A-conversion overlaps the DMA, ONE barrier,
// 48 MFMAs/wave, epilogue. Stalls pipeline across ~38 blocks/CU instead of serializing
// inside a 9-iteration loop. Epilogue byte-identical to R13 (write-optimal).
extern "C" __global__ __launch_bounds__(256, 4) void qkv_gemm(
    const float* __restrict__ x, const u16* __restrict__ w1tp, const float* __restrict__ b1,
    u16* __restrict__ qw, u16* __restrict__ kw, u16* __restrict__ vw){
  __shared__ u16 Bl[64 * BPAD];   // 25.6 KB
  const int tid = threadIdx.x;
  const int wid = tid >> 6, lane = tid & 63, l15 = lane & 15, l4 = lane >> 4;
  const int nt = blockIdx.y;
  const size_t row0 = (size_t)blockIdx.x * 128 + wid * 32;
  const f32x4 zz = {0.f, 0.f, 0.f, 0.f};

  // issue panel DMA first (stays in flight under the A-conversion VALU work)
  {
    const char* src = (const char*)w1tp + (size_t)nt * PANEL_BYTES + lane * 16;
    char* dst = (char*)Bl;
    for (int j = wid; j < 25; j += 4)
      gload_lds16(src + j * 1024, dst + j * 1024);
  }
  // A fragments: rows row0 + mf*16 + l15, k = kk*32 + l4*8 (fp32 -> bf16)
  bf16x8 af[2][6];
  #pragma unroll
  for (int mf = 0; mf < 2; ++mf){
    const float* src = x + (row0 + mf * 16 + l15) * CDIM + l4 * 8;
    #pragma unroll
    for (int kk = 0; kk < 6; ++kk){
      float4 f0 = *reinterpret_cast<const float4*>(src + kk * 32);
      float4 f1 = *reinterpret_cast<const float4*>(src + kk * 32 + 4);
      union { bf16x8 v; uint4 u; } cv;
      cv.u.x = pk2(f0.x, f0.y); cv.u.y = pk2(f0.z, f0.w);
      cv.u.z = pk2(f1.x, f1.y); cv.u.w = pk2(f1.z, f1.w);
      af[mf][kk] = cv.v;
    }
  }
  int bw_[2], n0_[2];
  #pragma unroll
  for (int mf = 0; mf < 2; ++mf){
    int t0 = (int)row0 + mf * 16 + l4 * 4;
    bw_[mf] = t0 / NTOK; n0_[mf] = t0 - bw_[mf] * NTOK;
  }
  __syncthreads();   // vmcnt(0) drain -> Bl ready

  f32x4 acc[2][4];
  #pragma unroll
  for (int mf = 0; mf < 2; ++mf)
    #pragma unroll
    for (int nf = 0; nf < 4; ++nf) acc[mf][nf] = zz;
  #pragma unroll
  for (int kk = 0; kk < 6; ++kk){
    bf16x8 bfr[4];
    #pragma unroll
    for (int nf = 0; nf < 4; ++nf)
      bfr[nf] = *reinterpret_cast<const bf16x8*>(&Bl[(nf * 16 + l15) * BPAD + kk * 32 + l4 * 8]);
    #pragma unroll
    for (int mf = 0; mf < 2; ++mf)
      #pragma unroll
      for (int nf = 0; nf < 4; ++nf)
        acc[mf][nf] = __builtin_amdgcn_mfma_f32_16x16x32_bf16(af[mf][kk], bfr[nf], acc[mf][nf], 0, 0, 0);
  }
  // epilogue (R13, write-optimal): nt 0-2 -> Q, 3-5 -> K, 6-8 -> V
  const int which = nt / 3;
  #pragma unroll
  for (int nf = 0; nf < 4; ++nf){
    int c = nt * 64 + nf * 16 + l15;
    int rem = c - which * CDIM;
    int hh = rem >> 5, chh = rem & 31;
    float bias = b1[c];
    if (which == 2){   // V transposed: one uint2 store per quad
      #pragma unroll
      for (int mf = 0; mf < 2; ++mf){
        uint2 pv;
        pv.x = pk2(acc[mf][nf][0] + bias, acc[mf][nf][1] + bias);
        pv.y = pk2(acc[mf][nf][2] + bias, acc[mf][nf][3] + bias);
        *reinterpret_cast<uint2*>(vw + (((size_t)bw_[mf] * NH + hh) * CH + chh) * NTOK + n0_[mf]) = pv;
      }
    } else {
      u16* base = (which == 0) ? qw : kw;
      float mult = (which == 0) ? (SCALE * LOG2E) : 1.0f;
      #pragma unroll
      for (int mf = 0; mf < 2; ++mf)
        #pragma unroll
        for (int r = 0; r < 4; ++r)
          base[(((size_t)bw_[mf] * NH + hh) * NTOK + n0_[mf] + r) * CH + chh] = f2b((acc[mf][nf][r] + bias) * mult);
    }
  }
}

// ---------------- K2: attention v7 (R13, proven) — 512-thr blocks, wave = one (b,h);
// bf16 comb C-init with cross-ti prefetch; even/odd V pairing + packed u32 stash.
extern "C" __global__ __launch_bounds__(512) void attn_kernel(
    const u16* __restrict__ qw, const u16* __restrict__ kw, const u16* __restrict__ vw,
    const u16* __restrict__ comb, float* __restrict__ outbuf){
  __shared__ u16 Pl[8][16][40];   // per-wave P chunk, pad 40 (10240 B)
  const int tid = threadIdx.x;
  const int wv = tid >> 6, lane = tid & 63, l15 = lane & 15, l4 = lane >> 4;
  const int gw = blockIdx.x * 8 + wv;       // 0..5759 = b*6+h
  const int b = gw / NH, h = gw - b * NH;
  const size_t qkbase = ((size_t)b * NH + h) * (NTOK * CH);
  const size_t vbase  = ((size_t)b * NH + h) * (CH * NTOK);
  const u16* cb = comb + ((size_t)((b / WLON) * NH + h)) * (5184 * 4);
  u16* Pw = &Pl[wv][0][0];
  u32* stash32 = reinterpret_cast<u32*>(outbuf);
  const f32x4 zz = {0.f, 0.f, 0.f, 0.f};

  // prologue: comb fragments for ti=0 (bf16, 2 dwords per tile)
  uint2 cc[9];
  #pragma unroll
  for (int nt = 0; nt < 9; ++nt)
    cc[nt] = *reinterpret_cast<const uint2*>(cb + ((size_t)nt * 64 + lane) * 4);

  #pragma unroll 1
  for (int ti = 0; ti < 9; ++ti){
    const int tin = (ti < 8) ? ti + 1 : ti;
    uint2 ccn[9];
    #pragma unroll
    for (int nt = 0; nt < 9; ++nt)
      ccn[nt] = *reinterpret_cast<const uint2*>(cb + ((size_t)(tin * 9 + nt) * 64 + lane) * 4);

    bf16x8 aq = *reinterpret_cast<const bf16x8*>(qw + qkbase + (ti * 16 + l15) * CH + l4 * 8);
    f32x4 s[9];
    #pragma unroll
    for (int nt = 0; nt < 9; ++nt){
      f32x4 cf;
      cf[0] = __uint_as_float(cc[nt].x << 16);
      cf[1] = __uint_as_float(cc[nt].x & 0xFFFF0000u);
      cf[2] = __uint_as_float(cc[nt].y << 16);
      cf[3] = __uint_as_float(cc[nt].y & 0xFFFF0000u);
      bf16x8 bk = *reinterpret_cast<const bf16x8*>(kw + qkbase + (nt * 16 + l15) * CH + l4 * 8);
      s[nt] = __builtin_amdgcn_mfma_f32_16x16x32_bf16(aq, bk, cf, 0, 0, 0);
    }
    float invs[4];
    #pragma unroll
    for (int r = 0; r < 4; ++r){
      float sum = 0.f;
      #pragma unroll
      for (int nt = 0; nt < 9; ++nt){
        float p = exp2f(s[nt][r]);
        s[nt][r] = p; sum += p;
      }
      #pragma unroll
      for (int off = 8; off; off >>= 1) sum += __shfl_xor(sum, off, 16);
      invs[r] = 1.0f / sum;   // applied at stash
    }
    f32x4 oe = zz, oo = zz;
    #pragma unroll
    for (int kk = 0; kk < 5; ++kk){
      #pragma unroll
      for (int r = 0; r < 4; ++r){
        Pw[(l4 * 4 + r) * 40 + l15] = f2b(s[2 * kk][r]);
        if (kk < 4) Pw[(l4 * 4 + r) * 40 + 16 + l15] = f2b(s[2 * kk + 1][r]);
      }
      int j0 = kk * 32 + l4 * 8;
      int jc = (j0 < NTOK) ? j0 : 0;          // clamp tail address (stay in-bounds)
      bf16x8 ap = *reinterpret_cast<const bf16x8*>(Pw + l15 * 40 + l4 * 8);
      bf16x8 bve = *reinterpret_cast<const bf16x8*>(vw + vbase + (size_t)(2 * l15) * NTOK + jc);
      bf16x8 bvo = *reinterpret_cast<const bf16x8*>(vw + vbase + (size_t)(2 * l15 + 1) * NTOK + jc);
      if (j0 >= NTOK) ap = bf16x8{0, 0, 0, 0, 0, 0, 0, 0};   // tail K=16: zero P side
      oe = __builtin_amdgcn_mfma_f32_16x16x32_bf16(ap, bve, oe, 0, 0, 0);
      oo = __builtin_amdgcn_mfma_f32_16x16x32_bf16(ap, bvo, oo, 0, 0, 0);
    }
    #pragma unroll
    for (int r = 0; r < 4; ++r){
      size_t t = (size_t)b * NTOK + ti * 16 + l4 * 4 + r;
      float is = invs[r];
      stash32[t * 192 + 96 + h * 16 + l15] = pk2(oe[r] * is, oo[r] * is);
    }
    #pragma unroll
    for (int nt = 0; nt < 9; ++nt) cc[nt] = ccn[nt];
  }
}

// ---------------- K3: out = attn_out @ w2 + b2 — B register-stationary, one-deep A prefetch.
extern "C" __global__ __launch_bounds__(256, 2) void proj_gemm(
    const u16* __restrict__ w2t, const float* __restrict__ b2, float* __restrict__ outbuf){
  const int tid = threadIdx.x;
  const int wid = tid >> 6, lane = tid & 63, l15 = lane & 15, l4 = lane >> 4;
  const int hb = blockIdx.y;             // col half: cols hb*96 .. +96
  const f32x4 zz = {0.f, 0.f, 0.f, 0.f};

  bf16x8 bfr[6][6];
  #pragma unroll
  for (int nf = 0; nf < 6; ++nf)
    #pragma unroll
    for (int kk = 0; kk < 6; ++kk)
      bfr[nf][kk] = *reinterpret_cast<const bf16x8*>(
          w2t + (size_t)(hb * 96 + nf * 16 + l15) * CDIM + kk * 32 + l4 * 8);

  const u16* stash = reinterpret_cast<const u16*>(outbuf);
  const size_t rbase = (size_t)blockIdx.x * 256 + wid * 64;

#define LOADA(dst, mt) { \
    const u16* src_ = stash + (rbase + (mt) * 16 + l15) * 384 + 192 + l4 * 8; \
    _Pragma("unroll") \
    for (int kk = 0; kk < 6; ++kk) dst[kk] = *reinterpret_cast<const bf16x8*>(src_ + kk * 32); }

#define COMPUTE(a_, mt) { \
    f32x4 acc[6]; \
    _Pragma("unroll") \
    for (int nf = 0; nf < 6; ++nf) acc[nf] = zz; \
    _Pragma("unroll") \
    for (int kk = 0; kk < 6; ++kk) \
      _Pragma("unroll") \
      for (int nf = 0; nf < 6; ++nf) \
        acc[nf] = __builtin_amdgcn_mfma_f32_16x16x32_bf16(a_[kk], bfr[nf][kk], acc[nf], 0, 0, 0); \
    _Pragma("unroll") \
    for (int nf = 0; nf < 6; ++nf){ \
      int c = hb * 96 + nf * 16 + l15; \
      float bias = b2[c]; \
      _Pragma("unroll") \
      for (int r = 0; r < 4; ++r) \
        outbuf[(rbase + (mt) * 16 + l4 * 4 + r) * CDIM + c] = acc[nf][r] + bias; } }

  bf16x8 a0[6], a1[6];
  LOADA(a0, 0)
  LOADA(a1, 1) COMPUTE(a0, 0)
  LOADA(a0, 2) COMPUTE(a1, 1)
  LOADA(a1, 3) COMPUTE(a0, 2)
  COMPUTE(a1, 3)
#undef LOADA
#undef COMPUTE
}

extern "C" void kernel_launch(void* const* d_in, const int* in_sizes, int n_in,
                              void* d_out, int out_size, void* d_ws, size_t ws_size,
                              hipStream_t stream){
  const float* x    = (const float*)d_in[0];
  const float* w1   = (const float*)d_in[1];
  const float* b1   = (const float*)d_in[2];
  const float* w2   = (const float*)d_in[3];
  const float* b2   = (const float*)d_in[4];
  const float* bt   = (const float*)d_in[5];
  const float* mask = (const float*)d_in[6];
  const int*   pidx = (const int*)d_in[7];
  (void)in_sizes; (void)n_in; (void)out_size; (void)ws_size;

  char* ws = (char*)d_ws;
  u16*   w1tp = (u16*)(ws + OFF_W1T);
  u16*   w2t  = (u16*)(ws + OFF_W2T);
  u16*   comb = (u16*)(ws + OFF_COMB);
  u16*   qw   = (u16*)(ws + OFF_Q);
  u16*   kw   = (u16*)(ws + OFF_K);
  u16*   vw   = (u16*)(ws + OFF_V);
  float* out = (float*)d_out;

  prep_weights<<<dim3(432), dim3(256), 0, stream>>>(w1, w2, w1tp, w2t);
  prep_comb<<<dim3(384, 27), dim3(192), 0, stream>>>(bt, mask, pidx, comb);
  qkv_gemm<<<dim3(1080, 9), dim3(256), 0, stream>>>(x, w1tp, b1, qw, kw, vw);
  attn_kernel<<<dim3(720), dim3(512), 0, stream>>>(qw, kw, vw, comb, out);
  proj_gemm<<<dim3(540, 2), dim3(256), 0, stream>>>(w2t, b2, out);
}

// Round 19
// 314.043 us; speedup vs baseline: 1.0724x; 1.0724x over previous
//
#include <hip/hip_runtime.h>

typedef __attribute__((ext_vector_type(8))) short bf16x8;
typedef __attribute__((ext_vector_type(4))) float f32x4;
typedef unsigned short u16;
typedef unsigned int u32;

#define NTOK 144
#define CDIM 192
#define NH 6
#define CH 32
#define C3 576
#define NWIN 64
#define WLON 15
#define SCALE 0.17677669529663687f
#define LOG2E 1.4426950408889634f

#define BPAD 200

// ws layout (bytes)
#define OFF_W1T  0u            // 576*192*2 = 221184
#define OFF_W2T  221184u       // 192*192*2 = 73728
#define OFF_COMB 294912u       // bf16 frag layout: 384*5184*4*2 = 15925248
#define OFF_Q    16220160u     // 960*6*144*32*2 = 53084160
#define OFF_K    69304320u
#define OFF_V    122388480u    // stored transposed: [b][h][ch][144]

__device__ __forceinline__ u16 f2b(float f){
  u32 u = __float_as_uint(f);
  u32 r = u + 0x7FFFu + ((u >> 16) & 1u);   // RNE
  return (u16)(r >> 16);
}
__device__ __forceinline__ u32 pk2(float a, float b){
  return (u32)f2b(a) | ((u32)f2b(b) << 16);
}

// ---------------- prep: transpose weights to bf16 (B-operand wants k-contiguous rows)
extern "C" __global__ __launch_bounds__(256) void prep_weights(
    const float* __restrict__ w1, const float* __restrict__ w2,
    u16* __restrict__ w1t, u16* __restrict__ w2t){
  int idx = blockIdx.x * 256 + threadIdx.x;
  if (idx < CDIM * C3){ int k = idx / C3;  int c = idx - k * C3;  w1t[c * CDIM + k] = f2b(w1[idx]); }
  if (idx < CDIM * CDIM){ int k = idx / CDIM; int c = idx - k * CDIM; w2t[c * CDIM + k] = f2b(w2[idx]); }
}

// ---------------- prep: comb (bias+mask)*LOG2E as bf16 in MFMA C-fragment layout.
extern "C" __global__ __launch_bounds__(192) void prep_comb(
    const float* __restrict__ bt, const float* __restrict__ mask,
    const int* __restrict__ pidx, u16* __restrict__ comb){
  int nwh = blockIdx.x;                 // 0..383 = nw*6+h
  int nw = nwh / NH, h = nwh - nw * NH;
  int tl = blockIdx.y * 192 + threadIdx.x;   // 0..5183 = (ti*9+nt)*64+lane
  int ti = tl / 576;
  int rem = tl - ti * 576;
  int nt = rem >> 6, lane = rem & 63;
  int ib = ti * 16 + ((lane >> 4) << 2);
  int j  = nt * 16 + (lane & 15);
  const float* mrow = mask + (size_t)(nw * WLON) * (NTOK * NTOK);
  float v[4];
  #pragma unroll
  for (int r = 0; r < 4; ++r){
    int e = (ib + r) * NTOK + j;
    int pi = pidx[e];
    v[r] = (bt[((size_t)pi * NWIN + nw) * NH + h] + mrow[e]) * LOG2E;
  }
  uint2 out; out.x = pk2(v[0], v[1]); out.y = pk2(v[2], v[3]);
  *reinterpret_cast<uint2*>(comb + ((size_t)nwh * 5184 + tl) * 4) = out;
}

// ---------------- K1: qkv v6 — single-buffer LDS (25.6 KB -> 6 blocks/CU ceiling) with
// T14 reg-prefetch staging: issue next panel's 6 uint4 loads, compute current panel's
// 48 MFMAs (hides load latency), barrier, ds_write, epilogue stores (hide lgkm), barrier.
// Epilogue byte-identical to R13 (write-optimal).
extern "C" __global__ __launch_bounds__(256, 4) void qkv_gemm(
    const float* __restrict__ x, const u16* __restrict__ w1t, const float* __restrict__ b1,
    u16* __restrict__ qw, u16* __restrict__ kw, u16* __restrict__ vw){
  __shared__ u16 Bl[64 * BPAD];   // 25.6 KB
  const int tid = threadIdx.x;
  const int wid = tid >> 6, lane = tid & 63, l15 = lane & 15, l4 = lane >> 4;
  const size_t row0 = (size_t)blockIdx.x * 128 + wid * 32;
  const f32x4 zz = {0.f, 0.f, 0.f, 0.f};

  // A fragments: rows row0 + mf*16 + l15, k = kk*32 + l4*8 (fp32 -> bf16 once)
  bf16x8 af[2][6];
  #pragma unroll
  for (int mf = 0; mf < 2; ++mf){
    const float* src = x + (row0 + mf * 16 + l15) * CDIM + l4 * 8;
    #pragma unroll
    for (int kk = 0; kk < 6; ++kk){
      float4 f0 = *reinterpret_cast<const float4*>(src + kk * 32);
      float4 f1 = *reinterpret_cast<const float4*>(src + kk * 32 + 4);
      union { bf16x8 v; uint4 u; } cv;
      cv.u.x = pk2(f0.x, f0.y); cv.u.y = pk2(f0.z, f0.w);
      cv.u.z = pk2(f1.x, f1.y); cv.u.w = pk2(f1.z, f1.w);
      af[mf][kk] = cv.v;
    }
  }
  int bw_[2], n0_[2];
  #pragma unroll
  for (int mf = 0; mf < 2; ++mf){
    int t0 = (int)row0 + mf * 16 + l4 * 4;
    bw_[mf] = t0 / NTOK; n0_[mf] = t0 - bw_[mf] * NTOK;
  }

  const int sr = tid >> 2, sq = tid & 3;      // staging role: 4 threads/row, 48 u16 each
  u16* sdst = Bl + sr * BPAD + sq * 48;
  { // prologue: stage panel 0
    const u16* src = w1t + (size_t)sr * CDIM + sq * 48;
    #pragma unroll
    for (int i = 0; i < 48; i += 8)
      *reinterpret_cast<uint4*>(sdst + i) = *reinterpret_cast<const uint4*>(src + i);
  }
  __syncthreads();

  #pragma unroll 1
  for (int nt = 0; nt < 9; ++nt){
    // T14: issue next panel's global loads first; they ride under this nt's MFMAs
    uint4 ldn[6];
    if (nt < 8){
      const u16* src = w1t + (size_t)((nt + 1) * 64 + sr) * CDIM + sq * 48;
      #pragma unroll
      for (int i = 0; i < 6; ++i)
        ldn[i] = *reinterpret_cast<const uint4*>(src + i * 8);
    }
    f32x4 acc[2][4];
    #pragma unroll
    for (int mf = 0; mf < 2; ++mf)
      #pragma unroll
      for (int nf = 0; nf < 4; ++nf) acc[mf][nf] = zz;
    #pragma unroll
    for (int kk = 0; kk < 6; ++kk){
      bf16x8 bfr[4];
      #pragma unroll
      for (int nf = 0; nf < 4; ++nf)
        bfr[nf] = *reinterpret_cast<const bf16x8*>(&Bl[(nf * 16 + l15) * BPAD + kk * 32 + l4 * 8]);
      #pragma unroll
      for (int mf = 0; mf < 2; ++mf)
        #pragma unroll
        for (int nf = 0; nf < 4; ++nf)
          acc[mf][nf] = __builtin_amdgcn_mfma_f32_16x16x32_bf16(af[mf][kk], bfr[nf], acc[mf][nf], 0, 0, 0);
    }
    __syncthreads();     // all waves done reading Bl
    if (nt < 8){         // ds_write the prefetched panel; lgkm drain hides under epilogue
      #pragma unroll
      for (int i = 0; i < 6; ++i)
        *reinterpret_cast<uint4*>(sdst + i * 8) = ldn[i];
    }
    // epilogue (R13, write-optimal): nt 0-2 -> Q, 3-5 -> K, 6-8 -> V
    int which = nt / 3;
    #pragma unroll
    for (int nf = 0; nf < 4; ++nf){
      int c = nt * 64 + nf * 16 + l15;
      int rem = c - which * CDIM;
      int hh = rem >> 5, chh = rem & 31;
      float bias = b1[c];
      if (which == 2){   // V transposed: one uint2 store per quad
        #pragma unroll
        for (int mf = 0; mf < 2; ++mf){
          uint2 pv;
          pv.x = pk2(acc[mf][nf][0] + bias, acc[mf][nf][1] + bias);
          pv.y = pk2(acc[mf][nf][2] + bias, acc[mf][nf][3] + bias);
          *reinterpret_cast<uint2*>(vw + (((size_t)bw_[mf] * NH + hh) * CH + chh) * NTOK + n0_[mf]) = pv;
        }
      } else {
        u16* base = (which == 0) ? qw : kw;
        float mult = (which == 0) ? (SCALE * LOG2E) : 1.0f;
        #pragma unroll
        for (int mf = 0; mf < 2; ++mf)
          #pragma unroll
          for (int r = 0; r < 4; ++r)
            base[(((size_t)bw_[mf] * NH + hh) * NTOK + n0_[mf] + r) * CH + chh] = f2b((acc[mf][nf][r] + bias) * mult);
      }
    }
    __syncthreads();     // panel nt+1 visible for next iteration
  }
}

// ---------------- K2: attention v7 (R13, proven) — 512-thr blocks, wave = one (b,h);
// bf16 comb C-init with cross-ti prefetch; even/odd V pairing + packed u32 stash.
extern "C" __global__ __launch_bounds__(512) void attn_kernel(
    const u16* __restrict__ qw, const u16* __restrict__ kw, const u16* __restrict__ vw,
    const u16* __restrict__ comb, float* __restrict__ outbuf){
  __shared__ u16 Pl[8][16][40];   // per-wave P chunk, pad 40 (10240 B)
  const int tid = threadIdx.x;
  const int wv = tid >> 6, lane = tid & 63, l15 = lane & 15, l4 = lane >> 4;
  const int gw = blockIdx.x * 8 + wv;       // 0..5759 = b*6+h
  const int b = gw / NH, h = gw - b * NH;
  const size_t qkbase = ((size_t)b * NH + h) * (NTOK * CH);
  const size_t vbase  = ((size_t)b * NH + h) * (CH * NTOK);
  const u16* cb = comb + ((size_t)((b / WLON) * NH + h)) * (5184 * 4);
  u16* Pw = &Pl[wv][0][0];
  u32* stash32 = reinterpret_cast<u32*>(outbuf);
  const f32x4 zz = {0.f, 0.f, 0.f, 0.f};

  // prologue: comb fragments for ti=0 (bf16, 2 dwords per tile)
  uint2 cc[9];
  #pragma unroll
  for (int nt = 0; nt < 9; ++nt)
    cc[nt] = *reinterpret_cast<const uint2*>(cb + ((size_t)nt * 64 + lane) * 4);

  #pragma unroll 1
  for (int ti = 0; ti < 9; ++ti){
    const int tin = (ti < 8) ? ti + 1 : ti;
    uint2 ccn[9];
    #pragma unroll
    for (int nt = 0; nt < 9; ++nt)
      ccn[nt] = *reinterpret_cast<const uint2*>(cb + ((size_t)(tin * 9 + nt) * 64 + lane) * 4);

    bf16x8 aq = *reinterpret_cast<const bf16x8*>(qw + qkbase + (ti * 16 + l15) * CH + l4 * 8);
    f32x4 s[9];
    #pragma unroll
    for (int nt = 0; nt < 9; ++nt){
      f32x4 cf;
      cf[0] = __uint_as_float(cc[nt].x << 16);
      cf[1] = __uint_as_float(cc[nt].x & 0xFFFF0000u);
      cf[2] = __uint_as_float(cc[nt].y << 16);
      cf[3] = __uint_as_float(cc[nt].y & 0xFFFF0000u);
      bf16x8 bk = *reinterpret_cast<const bf16x8*>(kw + qkbase + (nt * 16 + l15) * CH + l4 * 8);
      s[nt] = __builtin_amdgcn_mfma_f32_16x16x32_bf16(aq, bk, cf, 0, 0, 0);
    }
    float invs[4];
    #pragma unroll
    for (int r = 0; r < 4; ++r){
      float sum = 0.f;
      #pragma unroll
      for (int nt = 0; nt < 9; ++nt){
        float p = exp2f(s[nt][r]);
        s[nt][r] = p; sum += p;
      }
      #pragma unroll
      for (int off = 8; off; off >>= 1) sum += __shfl_xor(sum, off, 16);
      invs[r] = 1.0f / sum;   // applied at stash
    }
    f32x4 oe = zz, oo = zz;
    #pragma unroll
    for (int kk = 0; kk < 5; ++kk){
      #pragma unroll
      for (int r = 0; r < 4; ++r){
        Pw[(l4 * 4 + r) * 40 + l15] = f2b(s[2 * kk][r]);
        if (kk < 4) Pw[(l4 * 4 + r) * 40 + 16 + l15] = f2b(s[2 * kk + 1][r]);
      }
      int j0 = kk * 32 + l4 * 8;
      int jc = (j0 < NTOK) ? j0 : 0;          // clamp tail address (stay in-bounds)
      bf16x8 ap = *reinterpret_cast<const bf16x8*>(Pw + l15 * 40 + l4 * 8);
      bf16x8 bve = *reinterpret_cast<const bf16x8*>(vw + vbase + (size_t)(2 * l15) * NTOK + jc);
      bf16x8 bvo = *reinterpret_cast<const bf16x8*>(vw + vbase + (size_t)(2 * l15 + 1) * NTOK + jc);
      if (j0 >= NTOK) ap = bf16x8{0, 0, 0, 0, 0, 0, 0, 0};   // tail K=16: zero P side
      oe = __builtin_amdgcn_mfma_f32_16x16x32_bf16(ap, bve, oe, 0, 0, 0);
      oo = __builtin_amdgcn_mfma_f32_16x16x32_bf16(ap, bvo, oo, 0, 0, 0);
    }
    #pragma unroll
    for (int r = 0; r < 4; ++r){
      size_t t = (size_t)b * NTOK + ti * 16 + l4 * 4 + r;
      float is = invs[r];
      stash32[t * 192 + 96 + h * 16 + l15] = pk2(oe[r] * is, oo[r] * is);
    }
    #pragma unroll
    for (int nt = 0; nt < 9; ++nt) cc[nt] = ccn[nt];
  }
}

// ---------------- K3: out = attn_out @ w2 + b2 — B register-stationary, one-deep A prefetch.
extern "C" __global__ __launch_bounds__(256, 2) void proj_gemm(
    const u16* __restrict__ w2t, const float* __restrict__ b2, float* __restrict__ outbuf){
  const int tid = threadIdx.x;
  const int wid = tid >> 6, lane = tid & 63, l15 = lane & 15, l4 = lane >> 4;
  const int hb = blockIdx.y;             // col half: cols hb*96 .. +96
  const f32x4 zz = {0.f, 0.f, 0.f, 0.f};

  bf16x8 bfr[6][6];
  #pragma unroll
  for (int nf = 0; nf < 6; ++nf)
    #pragma unroll
    for (int kk = 0; kk < 6; ++kk)
      bfr[nf][kk] = *reinterpret_cast<const bf16x8*>(
          w2t + (size_t)(hb * 96 + nf * 16 + l15) * CDIM + kk * 32 + l4 * 8);

  const u16* stash = reinterpret_cast<const u16*>(outbuf);
  const size_t rbase = (size_t)blockIdx.x * 256 + wid * 64;

#define LOADA(dst, mt) { \
    const u16* src_ = stash + (rbase + (mt) * 16 + l15) * 384 + 192 + l4 * 8; \
    _Pragma("unroll") \
    for (int kk = 0; kk < 6; ++kk) dst[kk] = *reinterpret_cast<const bf16x8*>(src_ + kk * 32); }

#define COMPUTE(a_, mt) { \
    f32x4 acc[6]; \
    _Pragma("unroll") \
    for (int nf = 0; nf < 6; ++nf) acc[nf] = zz; \
    _Pragma("unroll") \
    for (int kk = 0; kk < 6; ++kk) \
      _Pragma("unroll") \
      for (int nf = 0; nf < 6; ++nf) \
        acc[nf] = __builtin_amdgcn_mfma_f32_16x16x32_bf16(a_[kk], bfr[nf][kk], acc[nf], 0, 0, 0); \
    _Pragma("unroll") \
    for (int nf = 0; nf < 6; ++nf){ \
      int c = hb * 96 + nf * 16 + l15; \
      float bias = b2[c]; \
      _Pragma("unroll") \
      for (int r = 0; r < 4; ++r) \
        outbuf[(rbase + (mt) * 16 + l4 * 4 + r) * CDIM + c] = acc[nf][r] + bias; } }

  bf16x8 a0[6], a1[6];
  LOADA(a0, 0)
  LOADA(a1, 1) COMPUTE(a0, 0)
  LOADA(a0, 2) COMPUTE(a1, 1)
  LOADA(a1, 3) COMPUTE(a0, 2)
  COMPUTE(a1, 3)
#undef LOADA
#undef COMPUTE
}

extern "C" void kernel_launch(void* const* d_in, const int* in_sizes, int n_in,
                              void* d_out, int out_size, void* d_ws, size_t ws_size,
                              hipStream_t stream){
  const float* x    = (const float*)d_in[0];
  const float* w1   = (const float*)d_in[1];
  const float* b1   = (const float*)d_in[2];
  const float* w2   = (const float*)d_in[3];
  const float* b2   = (const float*)d_in[4];
  const float* bt   = (const float*)d_in[5];
  const float* mask = (const float*)d_in[6];
  const int*   pidx = (const int*)d_in[7];
  (void)in_sizes; (void)n_in; (void)out_size; (void)ws_size;

  char* ws = (char*)d_ws;
  u16*   w1t  = (u16*)(ws + OFF_W1T);
  u16*   w2t  = (u16*)(ws + OFF_W2T);
  u16*   comb = (u16*)(ws + OFF_COMB);
  u16*   qw   = (u16*)(ws + OFF_Q);
  u16*   kw   = (u16*)(ws + OFF_K);
  u16*   vw   = (u16*)(ws + OFF_V);
  float* out = (float*)d_out;

  prep_weights<<<dim3(432), dim3(256), 0, stream>>>(w1, w2, w1t, w2t);
  prep_comb<<<dim3(384, 27), dim3(192), 0, stream>>>(bt, mask, pidx, comb);
  qkv_gemm<<<dim3(1080), dim3(256), 0, stream>>>(x, w1t, b1, qw, kw, vw);
  attn_kernel<<<dim3(720), dim3(512), 0, stream>>>(qw, kw, vw, comb, out);
  proj_gemm<<<dim3(540, 2), dim3(256), 0, stream>>>(w2t, b2, out);
}

// Round 20
// 243.825 us; speedup vs baseline: 1.3813x; 1.2880x over previous
//
#include <hip/hip_runtime.h>

typedef __attribute__((ext_vector_type(8))) short bf16x8;
typedef __attribute__((ext_vector_type(4))) float f32x4;
typedef unsigned short u16;
typedef unsigned int u32;

#define NTOK 144
#define CDIM 192
#define NH 6
#define CH 32
#define C3 576
#define NWIN 64
#define WLON 15
#define SCALE 0.17677669529663687f
#define LOG2E 1.4426950408889634f

// w1t panels stored pre-padded to the LDS image: 9 panels x [64 rows][200 u16] (pad zeroed)
#define BPAD 200
#define PANEL_BYTES 25600u     // 64*200*2

// ws layout (bytes)
#define OFF_W1T  0u            // 9*25600 = 230400
#define OFF_W2T  230400u       // 192*192*2 = 73728
#define OFF_COMB 304128u       // bf16 frag layout: 384*5184*4*2 = 15925248
#define OFF_Q    16229376u     // 960*6*144*32*2 = 53084160
#define OFF_K    69313536u
#define OFF_V    122397696u    // stored transposed: [b][h][ch][144]

__device__ __forceinline__ u16 f2b(float f){
  u32 u = __float_as_uint(f);
  u32 r = u + 0x7FFFu + ((u >> 16) & 1u);   // RNE
  return (u16)(r >> 16);
}
__device__ __forceinline__ u32 pk2(float a, float b){
  return (u32)f2b(a) | ((u32)f2b(b) << 16);
}
__device__ __forceinline__ void gload_lds16(const void* g, void* l){
  __builtin_amdgcn_global_load_lds(
      (const __attribute__((address_space(1))) unsigned int*)g,
      (__attribute__((address_space(3))) unsigned int*)l, 16, 0, 0);
}

// ---------------- prep: w1 -> padded bf16 panels (LDS image); w2 -> plain transposed bf16
extern "C" __global__ __launch_bounds__(256) void prep_weights(
    const float* __restrict__ w1, const float* __restrict__ w2,
    u16* __restrict__ w1tp, u16* __restrict__ w2t){
  int idx = blockIdx.x * 256 + threadIdx.x;
  if (idx < CDIM * C3){
    int k = idx / C3;  int c = idx - k * C3;
    w1tp[(size_t)c * BPAD + k] = f2b(w1[idx]);       // panel nt = rows c in [nt*64,(nt+1)*64)
  }
  if (idx < C3 * 8){                                  // zero row pads (cols 192..199)
    int c = idx >> 3, p = idx & 7;
    w1tp[(size_t)c * BPAD + CDIM + p] = 0;
  }
  if (idx < CDIM * CDIM){ int k = idx / CDIM; int c = idx - k * CDIM; w2t[c * CDIM + k] = f2b(w2[idx]); }
}

// ---------------- prep: comb (bias+mask)*LOG2E as bf16 in MFMA C-fragment layout.
extern "C" __global__ __launch_bounds__(192) void prep_comb(
    const float* __restrict__ bt, const float* __restrict__ mask,
    const int* __restrict__ pidx, u16* __restrict__ comb){
  int nwh = blockIdx.x;                 // 0..383 = nw*6+h
  int nw = nwh / NH, h = nwh - nw * NH;
  int tl = blockIdx.y * 192 + threadIdx.x;   // 0..5183 = (ti*9+nt)*64+lane
  int ti = tl / 576;
  int rem = tl - ti * 576;
  int nt = rem >> 6, lane = rem & 63;
  int ib = ti * 16 + ((lane >> 4) << 2);
  int j  = nt * 16 + (lane & 15);
  const float* mrow = mask + (size_t)(nw * WLON) * (NTOK * NTOK);
  float v[4];
  #pragma unroll
  for (int r = 0; r < 4; ++r){
    int e = (ib + r) * NTOK + j;
    int pi = pidx[e];
    v[r] = (bt[((size_t)pi * NWIN + nw) * NH + h] + mrow[e]) * LOG2E;
  }
  uint2 out; out.x = pk2(v[0], v[1]); out.y = pk2(v[2], v[3]);
  *reinterpret_cast<uint2*>(comb + ((size_t)nwh * 5184 + tl) * 4) = out;
}

// ---------------- K1: qkv v7 — R13's gll double-buffer + epilogue, M=192 tile:
// 4 waves x 48 rows -> 72 MFMAs/wave per nt (1.5x compute per drain), 720 blocks.
// Staging and per-element store pattern byte-identical to R13.
extern "C" __global__ __launch_bounds__(256, 3) void qkv_gemm(
    const float* __restrict__ x, const u16* __restrict__ w1tp, const float* __restrict__ b1,
    u16* __restrict__ qw, u16* __restrict__ kw, u16* __restrict__ vw){
  __shared__ u16 Bl[2][64 * BPAD];   // 2 x 25.6 KB
  const int tid = threadIdx.x;
  const int wid = tid >> 6, lane = tid & 63, l15 = lane & 15, l4 = lane >> 4;
  const size_t row0 = (size_t)blockIdx.x * 192 + wid * 48;
  const f32x4 zz = {0.f, 0.f, 0.f, 0.f};

  // A fragments: rows row0 + mf*16 + l15, k = kk*32 + l4*8 (fp32 -> bf16 once)
  bf16x8 af[3][6];
  #pragma unroll
  for (int mf = 0; mf < 3; ++mf){
    const float* src = x + (row0 + mf * 16 + l15) * CDIM + l4 * 8;
    #pragma unroll
    for (int kk = 0; kk < 6; ++kk){
      float4 f0 = *reinterpret_cast<const float4*>(src + kk * 32);
      float4 f1 = *reinterpret_cast<const float4*>(src + kk * 32 + 4);
      union { bf16x8 v; uint4 u; } cv;
      cv.u.x = pk2(f0.x, f0.y); cv.u.y = pk2(f0.z, f0.w);
      cv.u.z = pk2(f1.x, f1.y); cv.u.w = pk2(f1.z, f1.w);
      af[mf][kk] = cv.v;
    }
  }
  // hoisted output-row decomposition (quads never straddle windows: 4 | 144)
  int bw_[3], n0_[3];
  #pragma unroll
  for (int mf = 0; mf < 3; ++mf){
    int t0 = (int)row0 + mf * 16 + l4 * 4;
    bw_[mf] = t0 / NTOK; n0_[mf] = t0 - bw_[mf] * NTOK;
  }

  // prologue: DMA panel 0 (25 x 1KB wave-chunks)
  {
    const char* src = (const char*)w1tp + lane * 16;
    char* dst = (char*)&Bl[0][0];
    for (int j = wid; j < 25; j += 4)
      gload_lds16(src + j * 1024, dst + j * 1024);
  }

  int cur = 0;
  #pragma unroll 1
  for (int nt = 0; nt < 9; ++nt){
    __syncthreads();   // vmcnt(0) drain -> Bl[cur] ready; Bl[cur^1] free
    if (nt < 8){       // DMA next panel; stays in flight across the whole body
      const char* src = (const char*)w1tp + (size_t)(nt + 1) * PANEL_BYTES + lane * 16;
      char* dst = (char*)&Bl[cur ^ 1][0];
      for (int j = wid; j < 25; j += 4)
        gload_lds16(src + j * 1024, dst + j * 1024);
    }
    f32x4 acc[3][4];
    #pragma unroll
    for (int mf = 0; mf < 3; ++mf)
      #pragma unroll
      for (int nf = 0; nf < 4; ++nf) acc[mf][nf] = zz;
    #pragma unroll
    for (int kk = 0; kk < 6; ++kk){
      bf16x8 bfr[4];
      #pragma unroll
      for (int nf = 0; nf < 4; ++nf)
        bfr[nf] = *reinterpret_cast<const bf16x8*>(&Bl[cur][(nf * 16 + l15) * BPAD + kk * 32 + l4 * 8]);
      #pragma unroll
      for (int mf = 0; mf < 3; ++mf)
        #pragma unroll
        for (int nf = 0; nf < 4; ++nf)
          acc[mf][nf] = __builtin_amdgcn_mfma_f32_16x16x32_bf16(af[mf][kk], bfr[nf], acc[mf][nf], 0, 0, 0);
    }
    // epilogue (R13, write-optimal): nt 0-2 -> Q, 3-5 -> K, 6-8 -> V
    int which = nt / 3;
    #pragma unroll
    for (int nf = 0; nf < 4; ++nf){
      int c = nt * 64 + nf * 16 + l15;
      int rem = c - which * CDIM;
      int hh = rem >> 5, chh = rem & 31;
      float bias = b1[c];
      if (which == 2){   // V transposed: one uint2 store per quad
        #pragma unroll
        for (int mf = 0; mf < 3; ++mf){
          uint2 pv;
          pv.x = pk2(acc[mf][nf][0] + bias, acc[mf][nf][1] + bias);
          pv.y = pk2(acc[mf][nf][2] + bias, acc[mf][nf][3] + bias);
          *reinterpret_cast<uint2*>(vw + (((size_t)bw_[mf] * NH + hh) * CH + chh) * NTOK + n0_[mf]) = pv;
        }
      } else {
        u16* base = (which == 0) ? qw : kw;
        float mult = (which == 0) ? (SCALE * LOG2E) : 1.0f;
        #pragma unroll
        for (int mf = 0; mf < 3; ++mf)
          #pragma unroll
          for (int r = 0; r < 4; ++r)
            base[(((size_t)bw_[mf] * NH + hh) * NTOK + n0_[mf] + r) * CH + chh] = f2b((acc[mf][nf][r] + bias) * mult);
      }
    }
    cur ^= 1;
  }
}

// ---------------- K2: attention v7 (R13, proven) — 512-thr blocks, wave = one (b,h);
// bf16 comb C-init with cross-ti prefetch; even/odd V pairing + packed u32 stash.
extern "C" __global__ __launch_bounds__(512) void attn_kernel(
    const u16* __restrict__ qw, const u16* __restrict__ kw, const u16* __restrict__ vw,
    const u16* __restrict__ comb, float* __restrict__ outbuf){
  __shared__ u16 Pl[8][16][40];   // per-wave P chunk, pad 40 (10240 B)
  const int tid = threadIdx.x;
  const int wv = tid >> 6, lane = tid & 63, l15 = lane & 15, l4 = lane >> 4;
  const int gw = blockIdx.x * 8 + wv;       // 0..5759 = b*6+h
  const int b = gw / NH, h = gw - b * NH;
  const size_t qkbase = ((size_t)b * NH + h) * (NTOK * CH);
  const size_t vbase  = ((size_t)b * NH + h) * (CH * NTOK);
  const u16* cb = comb + ((size_t)((b / WLON) * NH + h)) * (5184 * 4);
  u16* Pw = &Pl[wv][0][0];
  u32* stash32 = reinterpret_cast<u32*>(outbuf);
  const f32x4 zz = {0.f, 0.f, 0.f, 0.f};

  // prologue: comb fragments for ti=0 (bf16, 2 dwords per tile)
  uint2 cc[9];
  #pragma unroll
  for (int nt = 0; nt < 9; ++nt)
    cc[nt] = *reinterpret_cast<const uint2*>(cb + ((size_t)nt * 64 + lane) * 4);

  #pragma unroll 1
  for (int ti = 0; ti < 9; ++ti){
    const int tin = (ti < 8) ? ti + 1 : ti;
    uint2 ccn[9];
    #pragma unroll
    for (int nt = 0; nt < 9; ++nt)
      ccn[nt] = *reinterpret_cast<const uint2*>(cb + ((size_t)(tin * 9 + nt) * 64 + lane) * 4);

    bf16x8 aq = *reinterpret_cast<const bf16x8*>(qw + qkbase + (ti * 16 + l15) * CH + l4 * 8);
    f32x4 s[9];
    #pragma unroll
    for (int nt = 0; nt < 9; ++nt){
      f32x4 cf;
      cf[0] = __uint_as_float(cc[nt].x << 16);
      cf[1] = __uint_as_float(cc[nt].x & 0xFFFF0000u);
      cf[2] = __uint_as_float(cc[nt].y << 16);
      cf[3] = __uint_as_float(cc[nt].y & 0xFFFF0000u);
      bf16x8 bk = *reinterpret_cast<const bf16x8*>(kw + qkbase + (nt * 16 + l15) * CH + l4 * 8);
      s[nt] = __builtin_amdgcn_mfma_f32_16x16x32_bf16(aq, bk, cf, 0, 0, 0);
    }
    float invs[4];
    #pragma unroll
    for (int r = 0; r < 4; ++r){
      float sum = 0.f;
      #pragma unroll
      for (int nt = 0; nt < 9; ++nt){
        float p = exp2f(s[nt][r]);
        s[nt][r] = p; sum += p;
      }
      #pragma unroll
      for (int off = 8; off; off >>= 1) sum += __shfl_xor(sum, off, 16);
      invs[r] = 1.0f / sum;   // applied at stash
    }
    f32x4 oe = zz, oo = zz;
    #pragma unroll
    for (int kk = 0; kk < 5; ++kk){
      #pragma unroll
      for (int r = 0; r < 4; ++r){
        Pw[(l4 * 4 + r) * 40 + l15] = f2b(s[2 * kk][r]);
        if (kk < 4) Pw[(l4 * 4 + r) * 40 + 16 + l15] = f2b(s[2 * kk + 1][r]);
      }
      int j0 = kk * 32 + l4 * 8;
      int jc = (j0 < NTOK) ? j0 : 0;          // clamp tail address (stay in-bounds)
      bf16x8 ap = *reinterpret_cast<const bf16x8*>(Pw + l15 * 40 + l4 * 8);
      bf16x8 bve = *reinterpret_cast<const bf16x8*>(vw + vbase + (size_t)(2 * l15) * NTOK + jc);
      bf16x8 bvo = *reinterpret_cast<const bf16x8*>(vw + vbase + (size_t)(2 * l15 + 1) * NTOK + jc);
      if (j0 >= NTOK) ap = bf16x8{0, 0, 0, 0, 0, 0, 0, 0};   // tail K=16: zero P side
      oe = __builtin_amdgcn_mfma_f32_16x16x32_bf16(ap, bve, oe, 0, 0, 0);
      oo = __builtin_amdgcn_mfma_f32_16x16x32_bf16(ap, bvo, oo, 0, 0, 0);
    }
    #pragma unroll
    for (int r = 0; r < 4; ++r){
      size_t t = (size_t)b * NTOK + ti * 16 + l4 * 4 + r;
      float is = invs[r];
      stash32[t * 192 + 96 + h * 16 + l15] = pk2(oe[r] * is, oo[r] * is);
    }
    #pragma unroll
    for (int nt = 0; nt < 9; ++nt) cc[nt] = ccn[nt];
  }
}

// ---------------- K3: out = attn_out @ w2 + b2 — B register-stationary, one-deep A prefetch.
extern "C" __global__ __launch_bounds__(256, 2) void proj_gemm(
    const u16* __restrict__ w2t, const float* __restrict__ b2, float* __restrict__ outbuf){
  const int tid = threadIdx.x;
  const int wid = tid >> 6, lane = tid & 63, l15 = lane & 15, l4 = lane >> 4;
  const int hb = blockIdx.y;             // col half: cols hb*96 .. +96
  const f32x4 zz = {0.f, 0.f, 0.f, 0.f};

  bf16x8 bfr[6][6];
  #pragma unroll
  for (int nf = 0; nf < 6; ++nf)
    #pragma unroll
    for (int kk = 0; kk < 6; ++kk)
      bfr[nf][kk] = *reinterpret_cast<const bf16x8*>(
          w2t + (size_t)(hb * 96 + nf * 16 + l15) * CDIM + kk * 32 + l4 * 8);

  const u16* stash = reinterpret_cast<const u16*>(outbuf);
  const size_t rbase = (size_t)blockIdx.x * 256 + wid * 64;

#define LOADA(dst, mt) { \
    const u16* src_ = stash + (rbase + (mt) * 16 + l15) * 384 + 192 + l4 * 8; \
    _Pragma("unroll") \
    for (int kk = 0; kk < 6; ++kk) dst[kk] = *reinterpret_cast<const bf16x8*>(src_ + kk * 32); }

#define COMPUTE(a_, mt) { \
    f32x4 acc[6]; \
    _Pragma("unroll") \
    for (int nf = 0; nf < 6; ++nf) acc[nf] = zz; \
    _Pragma("unroll") \
    for (int kk = 0; kk < 6; ++kk) \
      _Pragma("unroll") \
      for (int nf = 0; nf < 6; ++nf) \
        acc[nf] = __builtin_amdgcn_mfma_f32_16x16x32_bf16(a_[kk], bfr[nf][kk], acc[nf], 0, 0, 0); \
    _Pragma("unroll") \
    for (int nf = 0; nf < 6; ++nf){ \
      int c = hb * 96 + nf * 16 + l15; \
      float bias = b2[c]; \
      _Pragma("unroll") \
      for (int r = 0; r < 4; ++r) \
        outbuf[(rbase + (mt) * 16 + l4 * 4 + r) * CDIM + c] = acc[nf][r] + bias; } }

  bf16x8 a0[6], a1[6];
  LOADA(a0, 0)
  LOADA(a1, 1) COMPUTE(a0, 0)
  LOADA(a0, 2) COMPUTE(a1, 1)
  LOADA(a1, 3) COMPUTE(a0, 2)
  COMPUTE(a1, 3)
#undef LOADA
#undef COMPUTE
}

extern "C" void kernel_launch(void* const* d_in, const int* in_sizes, int n_in,
                              void* d_out, int out_size, void* d_ws, size_t ws_size,
                              hipStream_t stream){
  const float* x    = (const float*)d_in[0];
  const float* w1   = (const float*)d_in[1];
  const float* b1   = (const float*)d_in[2];
  const float* w2   = (const float*)d_in[3];
  const float* b2   = (const float*)d_in[4];
  const float* bt   = (const float*)d_in[5];
  const float* mask = (const float*)d_in[6];
  const int*   pidx = (const int*)d_in[7];
  (void)in_sizes; (void)n_in; (void)out_size; (void)ws_size;

  char* ws = (char*)d_ws;
  u16*   w1tp = (u16*)(ws + OFF_W1T);
  u16*   w2t  = (u16*)(ws + OFF_W2T);
  u16*   comb = (u16*)(ws + OFF_COMB);
  u16*   qw   = (u16*)(ws + OFF_Q);
  u16*   kw   = (u16*)(ws + OFF_K);
  u16*   vw   = (u16*)(ws + OFF_V);
  float* out = (float*)d_out;

  prep_weights<<<dim3(432), dim3(256), 0, stream>>>(w1, w2, w1tp, w2t);
  prep_comb<<<dim3(384, 27), dim3(192), 0, stream>>>(bt, mask, pidx, comb);
  qkv_gemm<<<dim3(720), dim3(256), 0, stream>>>(x, w1tp, b1, qw, kw, vw);
  attn_kernel<<<dim3(720), dim3(512), 0, stream>>>(qw, kw, vw, comb, out);
  proj_gemm<<<dim3(540, 2), dim3(256), 0, stream>>>(w2t, b2, out);
}

// Round 21
// 238.841 us; speedup vs baseline: 1.4101x; 1.0209x over previous
//
#include <hip/hip_runtime.h>

typedef __attribute__((ext_vector_type(8))) short bf16x8;
typedef __attribute__((ext_vector_type(4))) float f32x4;
typedef unsigned short u16;
typedef unsigned int u32;

#define NTOK 144
#define CDIM 192
#define NH 6
#define CH 32
#define C3 576
#define NWIN 64
#define WLON 15
#define SCALE 0.17677669529663687f
#define LOG2E 1.4426950408889634f

// w1t panels stored pre-padded to the LDS image: 9 panels x [64 rows][200 u16] (pad zeroed)
#define BPAD 200
#define PANEL_BYTES 25600u     // 64*200*2

// ws layout (bytes)
#define OFF_W1T  0u            // 9*25600 = 230400
#define OFF_W2T  230400u       // 192*192*2 = 73728
#define OFF_COMB 304128u       // bf16 frag layout: 384*5184*4*2 = 15925248
#define OFF_Q    16229376u     // 960*6*144*32*2 = 53084160
#define OFF_K    69313536u
#define OFF_V    122397696u    // stored transposed: [b][h][ch][144]

// qkv_aux block ranges
#define NB_QKV  720
#define NB_COMB 7776           // 384*5184/256
#define NB_W2T  144            // 192*192/256

__device__ __forceinline__ u16 f2b(float f){
  u32 u = __float_as_uint(f);
  u32 r = u + 0x7FFFu + ((u >> 16) & 1u);   // RNE
  return (u16)(r >> 16);
}
__device__ __forceinline__ u32 pk2(float a, float b){
  return (u32)f2b(a) | ((u32)f2b(b) << 16);
}
__device__ __forceinline__ void gload_lds16(const void* g, void* l){
  __builtin_amdgcn_global_load_lds(
      (const __attribute__((address_space(1))) unsigned int*)g,
      (__attribute__((address_space(3))) unsigned int*)l, 16, 0, 0);
}

// ---------------- prep: w1 -> padded bf16 panels only (w2t moved into qkv_aux)
extern "C" __global__ __launch_bounds__(256) void prep_w1(
    const float* __restrict__ w1, u16* __restrict__ w1tp){
  int idx = blockIdx.x * 256 + threadIdx.x;
  if (idx < CDIM * C3){
    int k = idx / C3;  int c = idx - k * C3;
    w1tp[(size_t)c * BPAD + k] = f2b(w1[idx]);       // panel nt = rows c in [nt*64,(nt+1)*64)
  }
  if (idx < C3 * 8){                                  // zero row pads (cols 192..199)
    int c = idx >> 3, p = idx & 7;
    w1tp[(size_t)c * BPAD + CDIM + p] = 0;
  }
}

// ---------------- K1: merged dispatch — qkv (blocks 0..719, R20 path verbatim) runs
// concurrently with prep_comb (blocks 720..8495) and w2^T transpose (blocks 8496..8639):
// the aux work hides under qkv's ~100 us instead of serializing before/after it.
extern "C" __global__ __launch_bounds__(256, 3) void qkv_aux(
    const float* __restrict__ x, const u16* __restrict__ w1tp, const float* __restrict__ b1,
    u16* __restrict__ qw, u16* __restrict__ kw, u16* __restrict__ vw,
    const float* __restrict__ bt, const float* __restrict__ mask,
    const int* __restrict__ pidx, u16* __restrict__ comb,
    const float* __restrict__ w2, u16* __restrict__ w2t){
  __shared__ u16 Bl[2][64 * BPAD];   // 2 x 25.6 KB (unused by aux blocks)
  const int bid = blockIdx.x;
  const int tid = threadIdx.x;

  if (bid >= NB_QKV){
    if (bid < NB_QKV + NB_COMB){
      // ---- prep_comb: comb[nwh][ti][nt][lane][r] = (bias+mask)*LOG2E as bf16 frags
      int idx = (bid - NB_QKV) * 256 + tid;        // 0 .. 384*5184-1
      int nwh = idx / 5184;
      int tl = idx - nwh * 5184;
      int nw = nwh / NH, h = nwh - nw * NH;
      int ti = tl / 576;
      int rem = tl - ti * 576;
      int nt = rem >> 6, lane = rem & 63;
      int ib = ti * 16 + ((lane >> 4) << 2);
      int j  = nt * 16 + (lane & 15);
      const float* mrow = mask + (size_t)(nw * WLON) * (NTOK * NTOK);
      float v[4];
      #pragma unroll
      for (int r = 0; r < 4; ++r){
        int e = (ib + r) * NTOK + j;
        int pi = pidx[e];
        v[r] = (bt[((size_t)pi * NWIN + nw) * NH + h] + mrow[e]) * LOG2E;
      }
      uint2 out; out.x = pk2(v[0], v[1]); out.y = pk2(v[2], v[3]);
      *reinterpret_cast<uint2*>(comb + ((size_t)nwh * 5184 + tl) * 4) = out;
    } else {
      // ---- w2 transpose: w2t[c][k] = bf16(w2[k][c])
      int idx = (bid - NB_QKV - NB_COMB) * 256 + tid;   // 0 .. 192*192-1
      int k = idx / CDIM, c = idx - k * CDIM;
      w2t[c * CDIM + k] = f2b(w2[idx]);
    }
    return;
  }

  // ---- qkv (R20, byte-identical): M=192 tile, gll double-buffer, write-optimal epilogue
  const int wid = tid >> 6, lane = tid & 63, l15 = lane & 15, l4 = lane >> 4;
  const size_t row0 = (size_t)bid * 192 + wid * 48;
  const f32x4 zz = {0.f, 0.f, 0.f, 0.f};

  bf16x8 af[3][6];
  #pragma unroll
  for (int mf = 0; mf < 3; ++mf){
    const float* src = x + (row0 + mf * 16 + l15) * CDIM + l4 * 8;
    #pragma unroll
    for (int kk = 0; kk < 6; ++kk){
      float4 f0 = *reinterpret_cast<const float4*>(src + kk * 32);
      float4 f1 = *reinterpret_cast<const float4*>(src + kk * 32 + 4);
      union { bf16x8 v; uint4 u; } cv;
      cv.u.x = pk2(f0.x, f0.y); cv.u.y = pk2(f0.z, f0.w);
      cv.u.z = pk2(f1.x, f1.y); cv.u.w = pk2(f1.z, f1.w);
      af[mf][kk] = cv.v;
    }
  }
  int bw_[3], n0_[3];
  #pragma unroll
  for (int mf = 0; mf < 3; ++mf){
    int t0 = (int)row0 + mf * 16 + l4 * 4;
    bw_[mf] = t0 / NTOK; n0_[mf] = t0 - bw_[mf] * NTOK;
  }

  {
    const char* src = (const char*)w1tp + lane * 16;
    char* dst = (char*)&Bl[0][0];
    for (int j = wid; j < 25; j += 4)
      gload_lds16(src + j * 1024, dst + j * 1024);
  }

  int cur = 0;
  #pragma unroll 1
  for (int nt = 0; nt < 9; ++nt){
    __syncthreads();   // vmcnt(0) drain -> Bl[cur] ready; Bl[cur^1] free
    if (nt < 8){       // DMA next panel; stays in flight across the whole body
      const char* src = (const char*)w1tp + (size_t)(nt + 1) * PANEL_BYTES + lane * 16;
      char* dst = (char*)&Bl[cur ^ 1][0];
      for (int j = wid; j < 25; j += 4)
        gload_lds16(src + j * 1024, dst + j * 1024);
    }
    f32x4 acc[3][4];
    #pragma unroll
    for (int mf = 0; mf < 3; ++mf)
      #pragma unroll
      for (int nf = 0; nf < 4; ++nf) acc[mf][nf] = zz;
    #pragma unroll
    for (int kk = 0; kk < 6; ++kk){
      bf16x8 bfr[4];
      #pragma unroll
      for (int nf = 0; nf < 4; ++nf)
        bfr[nf] = *reinterpret_cast<const bf16x8*>(&Bl[cur][(nf * 16 + l15) * BPAD + kk * 32 + l4 * 8]);
      #pragma unroll
      for (int mf = 0; mf < 3; ++mf)
        #pragma unroll
        for (int nf = 0; nf < 4; ++nf)
          acc[mf][nf] = __builtin_amdgcn_mfma_f32_16x16x32_bf16(af[mf][kk], bfr[nf], acc[mf][nf], 0, 0, 0);
    }
    int which = nt / 3;
    #pragma unroll
    for (int nf = 0; nf < 4; ++nf){
      int c = nt * 64 + nf * 16 + l15;
      int rem = c - which * CDIM;
      int hh = rem >> 5, chh = rem & 31;
      float bias = b1[c];
      if (which == 2){   // V transposed: one uint2 store per quad
        #pragma unroll
        for (int mf = 0; mf < 3; ++mf){
          uint2 pv;
          pv.x = pk2(acc[mf][nf][0] + bias, acc[mf][nf][1] + bias);
          pv.y = pk2(acc[mf][nf][2] + bias, acc[mf][nf][3] + bias);
          *reinterpret_cast<uint2*>(vw + (((size_t)bw_[mf] * NH + hh) * CH + chh) * NTOK + n0_[mf]) = pv;
        }
      } else {
        u16* base = (which == 0) ? qw : kw;
        float mult = (which == 0) ? (SCALE * LOG2E) : 1.0f;
        #pragma unroll
        for (int mf = 0; mf < 3; ++mf)
          #pragma unroll
          for (int r = 0; r < 4; ++r)
            base[(((size_t)bw_[mf] * NH + hh) * NTOK + n0_[mf] + r) * CH + chh] = f2b((acc[mf][nf][r] + bias) * mult);
      }
    }
    cur ^= 1;
  }
}

// ---------------- K2: attention v7 (R13, proven) — 512-thr blocks, wave = one (b,h);
// bf16 comb C-init with cross-ti prefetch; even/odd V pairing + packed u32 stash.
extern "C" __global__ __launch_bounds__(512) void attn_kernel(
    const u16* __restrict__ qw, const u16* __restrict__ kw, const u16* __restrict__ vw,
    const u16* __restrict__ comb, float* __restrict__ outbuf){
  __shared__ u16 Pl[8][16][40];   // per-wave P chunk, pad 40 (10240 B)
  const int tid = threadIdx.x;
  const int wv = tid >> 6, lane = tid & 63, l15 = lane & 15, l4 = lane >> 4;
  const int gw = blockIdx.x * 8 + wv;       // 0..5759 = b*6+h
  const int b = gw / NH, h = gw - b * NH;
  const size_t qkbase = ((size_t)b * NH + h) * (NTOK * CH);
  const size_t vbase  = ((size_t)b * NH + h) * (CH * NTOK);
  const u16* cb = comb + ((size_t)((b / WLON) * NH + h)) * (5184 * 4);
  u16* Pw = &Pl[wv][0][0];
  u32* stash32 = reinterpret_cast<u32*>(outbuf);
  const f32x4 zz = {0.f, 0.f, 0.f, 0.f};

  // prologue: comb fragments for ti=0 (bf16, 2 dwords per tile)
  uint2 cc[9];
  #pragma unroll
  for (int nt = 0; nt < 9; ++nt)
    cc[nt] = *reinterpret_cast<const uint2*>(cb + ((size_t)nt * 64 + lane) * 4);

  #pragma unroll 1
  for (int ti = 0; ti < 9; ++ti){
    const int tin = (ti < 8) ? ti + 1 : ti;
    uint2 ccn[9];
    #pragma unroll
    for (int nt = 0; nt < 9; ++nt)
      ccn[nt] = *reinterpret_cast<const uint2*>(cb + ((size_t)(tin * 9 + nt) * 64 + lane) * 4);

    bf16x8 aq = *reinterpret_cast<const bf16x8*>(qw + qkbase + (ti * 16 + l15) * CH + l4 * 8);
    f32x4 s[9];
    #pragma unroll
    for (int nt = 0; nt < 9; ++nt){
      f32x4 cf;
      cf[0] = __uint_as_float(cc[nt].x << 16);
      cf[1] = __uint_as_float(cc[nt].x & 0xFFFF0000u);
      cf[2] = __uint_as_float(cc[nt].y << 16);
      cf[3] = __uint_as_float(cc[nt].y & 0xFFFF0000u);
      bf16x8 bk = *reinterpret_cast<const bf16x8*>(kw + qkbase + (nt * 16 + l15) * CH + l4 * 8);
      s[nt] = __builtin_amdgcn_mfma_f32_16x16x32_bf16(aq, bk, cf, 0, 0, 0);
    }
    float invs[4];
    #pragma unroll
    for (int r = 0; r < 4; ++r){
      float sum = 0.f;
      #pragma unroll
      for (int nt = 0; nt < 9; ++nt){
        float p = exp2f(s[nt][r]);
        s[nt][r] = p; sum += p;
      }
      #pragma unroll
      for (int off = 8; off; off >>= 1) sum += __shfl_xor(sum, off, 16);
      invs[r] = 1.0f / sum;   // applied at stash
    }
    f32x4 oe = zz, oo = zz;
    #pragma unroll
    for (int kk = 0; kk < 5; ++kk){
      #pragma unroll
      for (int r = 0; r < 4; ++r){
        Pw[(l4 * 4 + r) * 40 + l15] = f2b(s[2 * kk][r]);
        if (kk < 4) Pw[(l4 * 4 + r) * 40 + 16 + l15] = f2b(s[2 * kk + 1][r]);
      }
      int j0 = kk * 32 + l4 * 8;
      int jc = (j0 < NTOK) ? j0 : 0;          // clamp tail address (stay in-bounds)
      bf16x8 ap = *reinterpret_cast<const bf16x8*>(Pw + l15 * 40 + l4 * 8);
      bf16x8 bve = *reinterpret_cast<const bf16x8*>(vw + vbase + (size_t)(2 * l15) * NTOK + jc);
      bf16x8 bvo = *reinterpret_cast<const bf16x8*>(vw + vbase + (size_t)(2 * l15 + 1) * NTOK + jc);
      if (j0 >= NTOK) ap = bf16x8{0, 0, 0, 0, 0, 0, 0, 0};   // tail K=16: zero P side
      oe = __builtin_amdgcn_mfma_f32_16x16x32_bf16(ap, bve, oe, 0, 0, 0);
      oo = __builtin_amdgcn_mfma_f32_16x16x32_bf16(ap, bvo, oo, 0, 0, 0);
    }
    #pragma unroll
    for (int r = 0; r < 4; ++r){
      size_t t = (size_t)b * NTOK + ti * 16 + l4 * 4 + r;
      float is = invs[r];
      stash32[t * 192 + 96 + h * 16 + l15] = pk2(oe[r] * is, oo[r] * is);
    }
    #pragma unroll
    for (int nt = 0; nt < 9; ++nt) cc[nt] = ccn[nt];
  }
}

// ---------------- K3: out = attn_out @ w2 + b2 — B register-stationary, one-deep A prefetch.
extern "C" __global__ __launch_bounds__(256, 2) void proj_gemm(
    const u16* __restrict__ w2t, const float* __restrict__ b2, float* __restrict__ outbuf){
  const int tid = threadIdx.x;
  const int wid = tid >> 6, lane = tid & 63, l15 = lane & 15, l4 = lane >> 4;
  const int hb = blockIdx.y;             // col half: cols hb*96 .. +96
  const f32x4 zz = {0.f, 0.f, 0.f, 0.f};

  bf16x8 bfr[6][6];
  #pragma unroll
  for (int nf = 0; nf < 6; ++nf)
    #pragma unroll
    for (int kk = 0; kk < 6; ++kk)
      bfr[nf][kk] = *reinterpret_cast<const bf16x8*>(
          w2t + (size_t)(hb * 96 + nf * 16 + l15) * CDIM + kk * 32 + l4 * 8);

  const u16* stash = reinterpret_cast<const u16*>(outbuf);
  const size_t rbase = (size_t)blockIdx.x * 256 + wid * 64;

#define LOADA(dst, mt) { \
    const u16* src_ = stash + (rbase + (mt) * 16 + l15) * 384 + 192 + l4 * 8; \
    _Pragma("unroll") \
    for (int kk = 0; kk < 6; ++kk) dst[kk] = *reinterpret_cast<const bf16x8*>(src_ + kk * 32); }

#define COMPUTE(a_, mt) { \
    f32x4 acc[6]; \
    _Pragma("unroll") \
    for (int nf = 0; nf < 6; ++nf) acc[nf] = zz; \
    _Pragma("unroll") \
    for (int kk = 0; kk < 6; ++kk) \
      _Pragma("unroll") \
      for (int nf = 0; nf < 6; ++nf) \
        acc[nf] = __builtin_amdgcn_mfma_f32_16x16x32_bf16(a_[kk], bfr[nf][kk], acc[nf], 0, 0, 0); \
    _Pragma("unroll") \
    for (int nf = 0; nf < 6; ++nf){ \
      int c = hb * 96 + nf * 16 + l15; \
      float bias = b2[c]; \
      _Pragma("unroll") \
      for (int r = 0; r < 4; ++r) \
        outbuf[(rbase + (mt) * 16 + l4 * 4 + r) * CDIM + c] = acc[nf][r] + bias; } }

  bf16x8 a0[6], a1[6];
  LOADA(a0, 0)
  LOADA(a1, 1) COMPUTE(a0, 0)
  LOADA(a0, 2) COMPUTE(a1, 1)
  LOADA(a1, 3) COMPUTE(a0, 2)
  COMPUTE(a1, 3)
#undef LOADA
#undef COMPUTE
}

extern "C" void kernel_launch(void* const* d_in, const int* in_sizes, int n_in,
                              void* d_out, int out_size, void* d_ws, size_t ws_size,
                              hipStream_t stream){
  const float* x    = (const float*)d_in[0];
  const float* w1   = (const float*)d_in[1];
  const float* b1   = (const float*)d_in[2];
  const float* w2   = (const float*)d_in[3];
  const float* b2   = (const float*)d_in[4];
  const float* bt   = (const float*)d_in[5];
  const float* mask = (const float*)d_in[6];
  const int*   pidx = (const int*)d_in[7];
  (void)in_sizes; (void)n_in; (void)out_size; (void)ws_size;

  char* ws = (char*)d_ws;
  u16*   w1tp = (u16*)(ws + OFF_W1T);
  u16*   w2t  = (u16*)(ws + OFF_W2T);
  u16*   comb = (u16*)(ws + OFF_COMB);
  u16*   qw   = (u16*)(ws + OFF_Q);
  u16*   kw   = (u16*)(ws + OFF_K);
  u16*   vw   = (u16*)(ws + OFF_V);
  float* out = (float*)d_out;

  prep_w1<<<dim3(432), dim3(256), 0, stream>>>(w1, w1tp);
  qkv_aux<<<dim3(NB_QKV + NB_COMB + NB_W2T), dim3(256), 0, stream>>>(
      x, w1tp, b1, qw, kw, vw, bt, mask, pidx, comb, w2, w2t);
  attn_kernel<<<dim3(720), dim3(512), 0, stream>>>(qw, kw, vw, comb, out);
  proj_gemm<<<dim3(540, 2), dim3(256), 0, stream>>>(w2t, b2, out);
}

// Round 22
// 235.655 us; speedup vs baseline: 1.4291x; 1.0135x over previous
//
#include <hip/hip_runtime.h>

typedef __attribute__((ext_vector_type(8))) short bf16x8;
typedef __attribute__((ext_vector_type(4))) float f32x4;
typedef unsigned short u16;
typedef unsigned int u32;

#define NTOK 144
#define CDIM 192
#define NH 6
#define CH 32
#define C3 576
#define NWIN 64
#define WLON 15
#define SCALE 0.17677669529663687f
#define LOG2E 1.4426950408889634f

// w1t panels stored pre-padded to the LDS image: 9 panels x [64 rows][200 u16] (pad zeroed)
#define BPAD 200
#define PANEL_BYTES 25600u     // 64*200*2

// ws layout (bytes)
#define OFF_W1T  0u            // 9*25600 = 230400
#define OFF_W2T  230400u       // 192*192*2 = 73728
#define OFF_COMB 304128u       // bf16 frag layout: 384*5184*4*2 = 15925248
#define OFF_Q    16229376u     // 960*6*144*32*2 = 53084160
#define OFF_K    69313536u
#define OFF_V    122397696u    // stored transposed: [b][h][ch][144]

// qkv_aux block ranges
#define NB_QKV  720
#define NB_COMB 7776           // 384*5184/256
#define NB_W2T  144            // 192*192/256

__device__ __forceinline__ u16 f2b(float f){
  u32 u = __float_as_uint(f);
  u32 r = u + 0x7FFFu + ((u >> 16) & 1u);   // RNE
  return (u16)(r >> 16);
}
__device__ __forceinline__ u32 pk2(float a, float b){
  return (u32)f2b(a) | ((u32)f2b(b) << 16);
}
__device__ __forceinline__ void gload_lds16(const void* g, void* l){
  __builtin_amdgcn_global_load_lds(
      (const __attribute__((address_space(1))) unsigned int*)g,
      (__attribute__((address_space(3))) unsigned int*)l, 16, 0, 0);
}

// ---------------- prep: w1 -> padded bf16 panels only (w2t lives in qkv_aux)
extern "C" __global__ __launch_bounds__(256) void prep_w1(
    const float* __restrict__ w1, u16* __restrict__ w1tp){
  int idx = blockIdx.x * 256 + threadIdx.x;
  if (idx < CDIM * C3){
    int k = idx / C3;  int c = idx - k * C3;
    w1tp[(size_t)c * BPAD + k] = f2b(w1[idx]);       // panel nt = rows c in [nt*64,(nt+1)*64)
  }
  if (idx < C3 * 8){                                  // zero row pads (cols 192..199)
    int c = idx >> 3, p = idx & 7;
    w1tp[(size_t)c * BPAD + CDIM + p] = 0;
  }
}

// ---------------- K1: merged dispatch — qkv (blocks 0..719, R20 path verbatim) runs
// concurrently with prep_comb (blocks 720..8495) and w2^T transpose (blocks 8496..8639).
extern "C" __global__ __launch_bounds__(256, 3) void qkv_aux(
    const float* __restrict__ x, const u16* __restrict__ w1tp, const float* __restrict__ b1,
    u16* __restrict__ qw, u16* __restrict__ kw, u16* __restrict__ vw,
    const float* __restrict__ bt, const float* __restrict__ mask,
    const int* __restrict__ pidx, u16* __restrict__ comb,
    const float* __restrict__ w2, u16* __restrict__ w2t){
  __shared__ u16 Bl[2][64 * BPAD];   // 2 x 25.6 KB (unused by aux blocks)
  const int bid = blockIdx.x;
  const int tid = threadIdx.x;

  if (bid >= NB_QKV){
    if (bid < NB_QKV + NB_COMB){
      // ---- prep_comb: comb[nwh][ti][nt][lane][r] = (bias+mask)*LOG2E as bf16 frags
      int idx = (bid - NB_QKV) * 256 + tid;        // 0 .. 384*5184-1
      int nwh = idx / 5184;
      int tl = idx - nwh * 5184;
      int nw = nwh / NH, h = nwh - nw * NH;
      int ti = tl / 576;
      int rem = tl - ti * 576;
      int nt = rem >> 6, lane = rem & 63;
      int ib = ti * 16 + ((lane >> 4) << 2);
      int j  = nt * 16 + (lane & 15);
      const float* mrow = mask + (size_t)(nw * WLON) * (NTOK * NTOK);
      float v[4];
      #pragma unroll
      for (int r = 0; r < 4; ++r){
        int e = (ib + r) * NTOK + j;
        int pi = pidx[e];
        v[r] = (bt[((size_t)pi * NWIN + nw) * NH + h] + mrow[e]) * LOG2E;
      }
      uint2 out; out.x = pk2(v[0], v[1]); out.y = pk2(v[2], v[3]);
      *reinterpret_cast<uint2*>(comb + ((size_t)nwh * 5184 + tl) * 4) = out;
    } else {
      // ---- w2 transpose: w2t[c][k] = bf16(w2[k][c])
      int idx = (bid - NB_QKV - NB_COMB) * 256 + tid;   // 0 .. 192*192-1
      int k = idx / CDIM, c = idx - k * CDIM;
      w2t[c * CDIM + k] = f2b(w2[idx]);
    }
    return;
  }

  // ---- qkv (R20, byte-identical): M=192 tile, gll double-buffer, write-optimal epilogue
  const int wid = tid >> 6, lane = tid & 63, l15 = lane & 15, l4 = lane >> 4;
  const size_t row0 = (size_t)bid * 192 + wid * 48;
  const f32x4 zz = {0.f, 0.f, 0.f, 0.f};

  bf16x8 af[3][6];
  #pragma unroll
  for (int mf = 0; mf < 3; ++mf){
    const float* src = x + (row0 + mf * 16 + l15) * CDIM + l4 * 8;
    #pragma unroll
    for (int kk = 0; kk < 6; ++kk){
      float4 f0 = *reinterpret_cast<const float4*>(src + kk * 32);
      float4 f1 = *reinterpret_cast<const float4*>(src + kk * 32 + 4);
      union { bf16x8 v; uint4 u; } cv;
      cv.u.x = pk2(f0.x, f0.y); cv.u.y = pk2(f0.z, f0.w);
      cv.u.z = pk2(f1.x, f1.y); cv.u.w = pk2(f1.z, f1.w);
      af[mf][kk] = cv.v;
    }
  }
  int bw_[3], n0_[3];
  #pragma unroll
  for (int mf = 0; mf < 3; ++mf){
    int t0 = (int)row0 + mf * 16 + l4 * 4;
    bw_[mf] = t0 / NTOK; n0_[mf] = t0 - bw_[mf] * NTOK;
  }

  {
    const char* src = (const char*)w1tp + lane * 16;
    char* dst = (char*)&Bl[0][0];
    for (int j = wid; j < 25; j += 4)
      gload_lds16(src + j * 1024, dst + j * 1024);
  }

  int cur = 0;
  #pragma unroll 1
  for (int nt = 0; nt < 9; ++nt){
    __syncthreads();   // vmcnt(0) drain -> Bl[cur] ready; Bl[cur^1] free
    if (nt < 8){       // DMA next panel; stays in flight across the whole body
      const char* src = (const char*)w1tp + (size_t)(nt + 1) * PANEL_BYTES + lane * 16;
      char* dst = (char*)&Bl[cur ^ 1][0];
      for (int j = wid; j < 25; j += 4)
        gload_lds16(src + j * 1024, dst + j * 1024);
    }
    f32x4 acc[3][4];
    #pragma unroll
    for (int mf = 0; mf < 3; ++mf)
      #pragma unroll
      for (int nf = 0; nf < 4; ++nf) acc[mf][nf] = zz;
    #pragma unroll
    for (int kk = 0; kk < 6; ++kk){
      bf16x8 bfr[4];
      #pragma unroll
      for (int nf = 0; nf < 4; ++nf)
        bfr[nf] = *reinterpret_cast<const bf16x8*>(&Bl[cur][(nf * 16 + l15) * BPAD + kk * 32 + l4 * 8]);
      #pragma unroll
      for (int mf = 0; mf < 3; ++mf)
        #pragma unroll
        for (int nf = 0; nf < 4; ++nf)
          acc[mf][nf] = __builtin_amdgcn_mfma_f32_16x16x32_bf16(af[mf][kk], bfr[nf], acc[mf][nf], 0, 0, 0);
    }
    int which = nt / 3;
    #pragma unroll
    for (int nf = 0; nf < 4; ++nf){
      int c = nt * 64 + nf * 16 + l15;
      int rem = c - which * CDIM;
      int hh = rem >> 5, chh = rem & 31;
      float bias = b1[c];
      if (which == 2){   // V transposed: one uint2 store per quad
        #pragma unroll
        for (int mf = 0; mf < 3; ++mf){
          uint2 pv;
          pv.x = pk2(acc[mf][nf][0] + bias, acc[mf][nf][1] + bias);
          pv.y = pk2(acc[mf][nf][2] + bias, acc[mf][nf][3] + bias);
          *reinterpret_cast<uint2*>(vw + (((size_t)bw_[mf] * NH + hh) * CH + chh) * NTOK + n0_[mf]) = pv;
        }
      } else {
        u16* base = (which == 0) ? qw : kw;
        float mult = (which == 0) ? (SCALE * LOG2E) : 1.0f;
        #pragma unroll
        for (int mf = 0; mf < 3; ++mf)
          #pragma unroll
          for (int r = 0; r < 4; ++r)
            base[(((size_t)bw_[mf] * NH + hh) * NTOK + n0_[mf] + r) * CH + chh] = f2b((acc[mf][nf][r] + bias) * mult);
      }
    }
    cur ^= 1;
  }
}

// ---------------- K2: attention v10 — same per-wave body as R13, 256-thr/4-wave blocks
// (1440 blocks = 5.6/CU): finer scheduling granularity fixes the 2.8-blocks/CU tail
// imbalance of the 512-thr shape. Wave body byte-identical.
extern "C" __global__ __launch_bounds__(256) void attn_kernel(
    const u16* __restrict__ qw, const u16* __restrict__ kw, const u16* __restrict__ vw,
    const u16* __restrict__ comb, float* __restrict__ outbuf){
  __shared__ u16 Pl[4][16][40];   // per-wave P chunk, pad 40 (5120 B)
  const int tid = threadIdx.x;
  const int wv = tid >> 6, lane = tid & 63, l15 = lane & 15, l4 = lane >> 4;
  const int gw = blockIdx.x * 4 + wv;       // 0..5759 = b*6+h
  const int b = gw / NH, h = gw - b * NH;
  const size_t qkbase = ((size_t)b * NH + h) * (NTOK * CH);
  const size_t vbase  = ((size_t)b * NH + h) * (CH * NTOK);
  const u16* cb = comb + ((size_t)((b / WLON) * NH + h)) * (5184 * 4);
  u16* Pw = &Pl[wv][0][0];
  u32* stash32 = reinterpret_cast<u32*>(outbuf);
  const f32x4 zz = {0.f, 0.f, 0.f, 0.f};

  // prologue: comb fragments for ti=0 (bf16, 2 dwords per tile)
  uint2 cc[9];
  #pragma unroll
  for (int nt = 0; nt < 9; ++nt)
    cc[nt] = *reinterpret_cast<const uint2*>(cb + ((size_t)nt * 64 + lane) * 4);

  #pragma unroll 1
  for (int ti = 0; ti < 9; ++ti){
    const int tin = (ti < 8) ? ti + 1 : ti;
    uint2 ccn[9];
    #pragma unroll
    for (int nt = 0; nt < 9; ++nt)
      ccn[nt] = *reinterpret_cast<const uint2*>(cb + ((size_t)(tin * 9 + nt) * 64 + lane) * 4);

    bf16x8 aq = *reinterpret_cast<const bf16x8*>(qw + qkbase + (ti * 16 + l15) * CH + l4 * 8);
    f32x4 s[9];
    #pragma unroll
    for (int nt = 0; nt < 9; ++nt){
      f32x4 cf;
      cf[0] = __uint_as_float(cc[nt].x << 16);
      cf[1] = __uint_as_float(cc[nt].x & 0xFFFF0000u);
      cf[2] = __uint_as_float(cc[nt].y << 16);
      cf[3] = __uint_as_float(cc[nt].y & 0xFFFF0000u);
      bf16x8 bk = *reinterpret_cast<const bf16x8*>(kw + qkbase + (nt * 16 + l15) * CH + l4 * 8);
      s[nt] = __builtin_amdgcn_mfma_f32_16x16x32_bf16(aq, bk, cf, 0, 0, 0);
    }
    float invs[4];
    #pragma unroll
    for (int r = 0; r < 4; ++r){
      float sum = 0.f;
      #pragma unroll
      for (int nt = 0; nt < 9; ++nt){
        float p = exp2f(s[nt][r]);
        s[nt][r] = p; sum += p;
      }
      #pragma unroll
      for (int off = 8; off; off >>= 1) sum += __shfl_xor(sum, off, 16);
      invs[r] = 1.0f / sum;   // applied at stash
    }
    f32x4 oe = zz, oo = zz;
    #pragma unroll
    for (int kk = 0; kk < 5; ++kk){
      #pragma unroll
      for (int r = 0; r < 4; ++r){
        Pw[(l4 * 4 + r) * 40 + l15] = f2b(s[2 * kk][r]);
        if (kk < 4) Pw[(l4 * 4 + r) * 40 + 16 + l15] = f2b(s[2 * kk + 1][r]);
      }
      int j0 = kk * 32 + l4 * 8;
      int jc = (j0 < NTOK) ? j0 : 0;          // clamp tail address (stay in-bounds)
      bf16x8 ap = *reinterpret_cast<const bf16x8*>(Pw + l15 * 40 + l4 * 8);
      bf16x8 bve = *reinterpret_cast<const bf16x8*>(vw + vbase + (size_t)(2 * l15) * NTOK + jc);
      bf16x8 bvo = *reinterpret_cast<const bf16x8*>(vw + vbase + (size_t)(2 * l15 + 1) * NTOK + jc);
      if (j0 >= NTOK) ap = bf16x8{0, 0, 0, 0, 0, 0, 0, 0};   // tail K=16: zero P side
      oe = __builtin_amdgcn_mfma_f32_16x16x32_bf16(ap, bve, oe, 0, 0, 0);
      oo = __builtin_amdgcn_mfma_f32_16x16x32_bf16(ap, bvo, oo, 0, 0, 0);
    }
    #pragma unroll
    for (int r = 0; r < 4; ++r){
      size_t t = (size_t)b * NTOK + ti * 16 + l4 * 4 + r;
      float is = invs[r];
      stash32[t * 192 + 96 + h * 16 + l15] = pk2(oe[r] * is, oo[r] * is);
    }
    #pragma unroll
    for (int nt = 0; nt < 9; ++nt) cc[nt] = ccn[nt];
  }
}

// ---------------- K3: out = attn_out @ w2 + b2 — B register-stationary, one-deep A prefetch.
extern "C" __global__ __launch_bounds__(256, 2) void proj_gemm(
    const u16* __restrict__ w2t, const float* __restrict__ b2, float* __restrict__ outbuf){
  const int tid = threadIdx.x;
  const int wid = tid >> 6, lane = tid & 63, l15 = lane & 15, l4 = lane >> 4;
  const int hb = blockIdx.y;             // col half: cols hb*96 .. +96
  const f32x4 zz = {0.f, 0.f, 0.f, 0.f};

  bf16x8 bfr[6][6];
  #pragma unroll
  for (int nf = 0; nf < 6; ++nf)
    #pragma unroll
    for (int kk = 0; kk < 6; ++kk)
      bfr[nf][kk] = *reinterpret_cast<const bf16x8*>(
          w2t + (size_t)(hb * 96 + nf * 16 + l15) * CDIM + kk * 32 + l4 * 8);

  const u16* stash = reinterpret_cast<const u16*>(outbuf);
  const size_t rbase = (size_t)blockIdx.x * 256 + wid * 64;

#define LOADA(dst, mt) { \
    const u16* src_ = stash + (rbase + (mt) * 16 + l15) * 384 + 192 + l4 * 8; \
    _Pragma("unroll") \
    for (int kk = 0; kk < 6; ++kk) dst[kk] = *reinterpret_cast<const bf16x8*>(src_ + kk * 32); }

#define COMPUTE(a_, mt) { \
    f32x4 acc[6]; \
    _Pragma("unroll") \
    for (int nf = 0; nf < 6; ++nf) acc[nf] = zz; \
    _Pragma("unroll") \
    for (int kk = 0; kk < 6; ++kk) \
      _Pragma("unroll") \
      for (int nf = 0; nf < 6; ++nf) \
        acc[nf] = __builtin_amdgcn_mfma_f32_16x16x32_bf16(a_[kk], bfr[nf][kk], acc[nf], 0, 0, 0); \
    _Pragma("unroll") \
    for (int nf = 0; nf < 6; ++nf){ \
      int c = hb * 96 + nf * 16 + l15; \
      float bias = b2[c]; \
      _Pragma("unroll") \
      for (int r = 0; r < 4; ++r) \
        outbuf[(rbase + (mt) * 16 + l4 * 4 + r) * CDIM + c] = acc[nf][r] + bias; } }

  bf16x8 a0[6], a1[6];
  LOADA(a0, 0)
  LOADA(a1, 1) COMPUTE(a0, 0)
  LOADA(a0, 2) COMPUTE(a1, 1)
  LOADA(a1, 3) COMPUTE(a0, 2)
  COMPUTE(a1, 3)
#undef LOADA
#undef COMPUTE
}

extern "C" void kernel_launch(void* const* d_in, const int* in_sizes, int n_in,
                              void* d_out, int out_size, void* d_ws, size_t ws_size,
                              hipStream_t stream){
  const float* x    = (const float*)d_in[0];
  const float* w1   = (const float*)d_in[1];
  const float* b1   = (const float*)d_in[2];
  const float* w2   = (const float*)d_in[3];
  const float* b2   = (const float*)d_in[4];
  const float* bt   = (const float*)d_in[5];
  const float* mask = (const float*)d_in[6];
  const int*   pidx = (const int*)d_in[7];
  (void)in_sizes; (void)n_in; (void)out_size; (void)ws_size;

  char* ws = (char*)d_ws;
  u16*   w1tp = (u16*)(ws + OFF_W1T);
  u16*   w2t  = (u16*)(ws + OFF_W2T);
  u16*   comb = (u16*)(ws + OFF_COMB);
  u16*   qw   = (u16*)(ws + OFF_Q);
  u16*   kw   = (u16*)(ws + OFF_K);
  u16*   vw   = (u16*)(ws + OFF_V);
  float* out = (float*)d_out;

  prep_w1<<<dim3(432), dim3(256), 0, stream>>>(w1, w1tp);
  qkv_aux<<<dim3(NB_QKV + NB_COMB + NB_W2T), dim3(256), 0, stream>>>(
      x, w1tp, b1, qw, kw, vw, bt, mask, pidx, comb, w2, w2t);
  attn_kernel<<<dim3(1440), dim3(256), 0, stream>>>(qw, kw, vw, comb, out);
  proj_gemm<<<dim3(540, 2), dim3(256), 0, stream>>>(w2t, b2, out);
}